// Round 1
// baseline (271.792 us; speedup 1.0000x reference)
//
#include <hip/hip_runtime.h>

#define Bn 4
#define Nn 4096000
#define Kn 409664
#define R0c 3686399u
#define R1c 3686400u

// ws offsets (u32 units)
#define H1_OFF 0          // B*2048
#define H2_OFF 8192       // B*2*2048
#define H3_OFF 24576      // B*2*1024
#define ST_OFF 32768      // B*4  {key/prefix0, rem0, key/prefix1, rem1}
#define CNT_OFF 32784     // B
#define BC_OFF 32788      // B*1000

#define OUT_SP  ((size_t)Bn * Kn * 5)
#define OUT_VAL ((size_t)Bn * Kn * 9)

__device__ __forceinline__ unsigned fkey(float x) {
    unsigned u = __float_as_uint(x);
    return u ^ ((unsigned)((int)u >> 31) | 0x80000000u);
}
__device__ __forceinline__ float keyf(unsigned k) {
    unsigned u = (k & 0x80000000u) ? (k & 0x7FFFFFFFu) : ~k;
    return __uint_as_float(u);
}

// ---------------- histogram pass 1: top 11 bits ----------------
__global__ void hist1_k(const float* __restrict__ cube, unsigned* __restrict__ ws) {
    __shared__ unsigned h[2048];
    int tid = threadIdx.x, blk = blockIdx.x;
    int b = blk / 250, c = blk % 250;
    for (int j = tid; j < 2048; j += 256) h[j] = 0;
    __syncthreads();
    const float4* p = (const float4*)(cube + (size_t)b * Nn + (size_t)c * 16384);
    for (int it = 0; it < 16; ++it) {
        float4 v = p[it * 256 + tid];
        atomicAdd(&h[fkey(v.x) >> 21], 1u);
        atomicAdd(&h[fkey(v.y) >> 21], 1u);
        atomicAdd(&h[fkey(v.z) >> 21], 1u);
        atomicAdd(&h[fkey(v.w) >> 21], 1u);
    }
    __syncthreads();
    unsigned* g = ws + H1_OFF + b * 2048;
    for (int j = tid; j < 2048; j += 256) if (h[j]) atomicAdd(&g[j], h[j]);
}

// ---------------- pick from pass-1 histogram (both ranks) ----------------
__global__ void pick1_k(unsigned* __restrict__ ws) {
    __shared__ unsigned sh[256];
    int tid = threadIdx.x, b = blockIdx.x;
    const unsigned* hist = ws + H1_OFF + b * 2048;
    unsigned loc[8], lsum = 0;
    for (int j = 0; j < 8; ++j) { loc[j] = hist[tid * 8 + j]; lsum += loc[j]; }
    sh[tid] = lsum; __syncthreads();
    for (int off = 1; off < 256; off <<= 1) {
        unsigned v = (tid >= off) ? sh[tid - off] : 0u; __syncthreads();
        sh[tid] += v; __syncthreads();
    }
    unsigned base = tid ? sh[tid - 1] : 0u;
    unsigned ranks[2] = {R0c, R1c};
    for (int pth = 0; pth < 2; ++pth) {
        unsigned r = ranks[pth];
        if (r >= base && r < base + lsum) {
            unsigned cacc = base;
            for (int j = 0; j < 8; ++j) {
                if (r < cacc + loc[j]) {
                    ws[ST_OFF + b * 4 + pth * 2] = (unsigned)(tid * 8 + j);
                    ws[ST_OFF + b * 4 + pth * 2 + 1] = r - cacc;
                    break;
                }
                cacc += loc[j];
            }
        }
    }
}

// ---------------- histogram pass 2: middle 11 bits, two prefix paths ----------------
__global__ void hist2_k(const float* __restrict__ cube, unsigned* __restrict__ ws) {
    __shared__ unsigned h0[2048], h1[2048];
    int tid = threadIdx.x, blk = blockIdx.x;
    int b = blk / 250, c = blk % 250;
    unsigned p0 = ws[ST_OFF + b * 4 + 0];
    unsigned p1 = ws[ST_OFF + b * 4 + 2];
    for (int j = tid; j < 2048; j += 256) { h0[j] = 0; h1[j] = 0; }
    __syncthreads();
    const float4* p = (const float4*)(cube + (size_t)b * Nn + (size_t)c * 16384);
    for (int it = 0; it < 16; ++it) {
        float4 v = p[it * 256 + tid];
        float vv[4] = {v.x, v.y, v.z, v.w};
        for (int q = 0; q < 4; ++q) {
            unsigned k = fkey(vv[q]);
            unsigned top = k >> 21;
            unsigned mid = (k >> 10) & 0x7FFu;
            if (top == p0) atomicAdd(&h0[mid], 1u);
            if (top == p1) atomicAdd(&h1[mid], 1u);
        }
    }
    __syncthreads();
    unsigned* g0 = ws + H2_OFF + (b * 2) * 2048;
    unsigned* g1 = g0 + 2048;
    for (int j = tid; j < 2048; j += 256) {
        if (h0[j]) atomicAdd(&g0[j], h0[j]);
        if (h1[j]) atomicAdd(&g1[j], h1[j]);
    }
}

__global__ void pick2_k(unsigned* __restrict__ ws) {
    __shared__ unsigned sh[256];
    int tid = threadIdx.x; int b = blockIdx.x >> 1, pth = blockIdx.x & 1;
    const unsigned* hist = ws + H2_OFF + (b * 2 + pth) * 2048;
    unsigned r = ws[ST_OFF + b * 4 + pth * 2 + 1];
    unsigned pref = ws[ST_OFF + b * 4 + pth * 2];
    unsigned loc[8], lsum = 0;
    for (int j = 0; j < 8; ++j) { loc[j] = hist[tid * 8 + j]; lsum += loc[j]; }
    sh[tid] = lsum; __syncthreads();
    for (int off = 1; off < 256; off <<= 1) {
        unsigned v = (tid >= off) ? sh[tid - off] : 0u; __syncthreads();
        sh[tid] += v; __syncthreads();
    }
    unsigned base = tid ? sh[tid - 1] : 0u;
    if (r >= base && r < base + lsum) {
        unsigned cacc = base;
        for (int j = 0; j < 8; ++j) {
            if (r < cacc + loc[j]) {
                ws[ST_OFF + b * 4 + pth * 2] = (pref << 11) | (unsigned)(tid * 8 + j);
                ws[ST_OFF + b * 4 + pth * 2 + 1] = r - cacc;
                break;
            }
            cacc += loc[j];
        }
    }
}

// ---------------- histogram pass 3: low 10 bits ----------------
__global__ void hist3_k(const float* __restrict__ cube, unsigned* __restrict__ ws) {
    __shared__ unsigned h0[1024], h1[1024];
    int tid = threadIdx.x, blk = blockIdx.x;
    int b = blk / 250, c = blk % 250;
    unsigned p0 = ws[ST_OFF + b * 4 + 0];
    unsigned p1 = ws[ST_OFF + b * 4 + 2];
    for (int j = tid; j < 1024; j += 256) { h0[j] = 0; h1[j] = 0; }
    __syncthreads();
    const float4* p = (const float4*)(cube + (size_t)b * Nn + (size_t)c * 16384);
    for (int it = 0; it < 16; ++it) {
        float4 v = p[it * 256 + tid];
        float vv[4] = {v.x, v.y, v.z, v.w};
        for (int q = 0; q < 4; ++q) {
            unsigned k = fkey(vv[q]);
            unsigned top = k >> 10;
            unsigned lowb = k & 0x3FFu;
            if (top == p0) atomicAdd(&h0[lowb], 1u);
            if (top == p1) atomicAdd(&h1[lowb], 1u);
        }
    }
    __syncthreads();
    unsigned* g0 = ws + H3_OFF + (b * 2) * 1024;
    unsigned* g1 = g0 + 1024;
    for (int j = tid; j < 1024; j += 256) {
        if (h0[j]) atomicAdd(&g0[j], h0[j]);
        if (h1[j]) atomicAdd(&g1[j], h1[j]);
    }
}

__global__ void pick3_k(unsigned* __restrict__ ws) {
    __shared__ unsigned sh[256];
    int tid = threadIdx.x; int b = blockIdx.x >> 1, pth = blockIdx.x & 1;
    const unsigned* hist = ws + H3_OFF + (b * 2 + pth) * 1024;
    unsigned r = ws[ST_OFF + b * 4 + pth * 2 + 1];
    unsigned pref = ws[ST_OFF + b * 4 + pth * 2];
    unsigned loc[4], lsum = 0;
    for (int j = 0; j < 4; ++j) { loc[j] = hist[tid * 4 + j]; lsum += loc[j]; }
    sh[tid] = lsum; __syncthreads();
    for (int off = 1; off < 256; off <<= 1) {
        unsigned v = (tid >= off) ? sh[tid - off] : 0u; __syncthreads();
        sh[tid] += v; __syncthreads();
    }
    unsigned base = tid ? sh[tid - 1] : 0u;
    if (r >= base && r < base + lsum) {
        unsigned cacc = base;
        for (int j = 0; j < 4; ++j) {
            if (r < cacc + loc[j]) {
                ws[ST_OFF + b * 4 + pth * 2] = (pref << 10) | (unsigned)(tid * 4 + j);
                break;
            }
            cacc += loc[j];
        }
    }
}

// ---------------- per-block mask counts ----------------
__global__ void count_k(const float* __restrict__ cube, unsigned* __restrict__ ws) {
    __shared__ unsigned sh[256];
    int tid = threadIdx.x, blk = blockIdx.x;
    int b = blk / 1000, c = blk % 1000;
    float vlo = keyf(ws[ST_OFF + b * 4 + 0]);
    float vhi = keyf(ws[ST_OFF + b * 4 + 2]);
    double thr = (double)vlo + 0.1 * ((double)vhi - (double)vlo);
    const float4* p = (const float4*)(cube + (size_t)b * Nn + (size_t)c * 4096);
    unsigned cnt = 0;
    for (int it = 0; it < 4; ++it) {
        float4 v = p[it * 256 + tid];
        cnt += (unsigned)((double)v.x > thr) + (unsigned)((double)v.y > thr)
             + (unsigned)((double)v.z > thr) + (unsigned)((double)v.w > thr);
    }
    sh[tid] = cnt; __syncthreads();
    for (int off = 128; off > 0; off >>= 1) {
        if (tid < off) sh[tid] += sh[tid + off];
        __syncthreads();
    }
    if (tid == 0) ws[BC_OFF + b * 1000 + c] = sh[0];
}

// ---------------- exclusive scan of 1000 block counts per sample ----------------
__global__ void scan_k(unsigned* __restrict__ ws) {
    __shared__ unsigned sh[256];
    int tid = threadIdx.x, b = blockIdx.x;
    unsigned* bc = ws + BC_OFF + b * 1000;
    unsigned loc[4], lsum = 0;
    for (int j = 0; j < 4; ++j) {
        int idx = tid * 4 + j;
        loc[j] = (idx < 1000) ? bc[idx] : 0u;
        lsum += loc[j];
    }
    sh[tid] = lsum; __syncthreads();
    for (int off = 1; off < 256; off <<= 1) {
        unsigned v = (tid >= off) ? sh[tid - off] : 0u; __syncthreads();
        sh[tid] += v; __syncthreads();
    }
    unsigned run = tid ? sh[tid - 1] : 0u;
    for (int j = 0; j < 4; ++j) {
        int idx = tid * 4 + j;
        if (idx < 1000) bc[idx] = run;
        run += loc[j];
    }
    if (tid == 255) ws[CNT_OFF + b] = sh[255];
}

// ---------------- ordered scatter ----------------
__global__ void scatter_k(const float* __restrict__ cube, const float* __restrict__ dop,
                          float* __restrict__ out, const unsigned* __restrict__ ws) {
    __shared__ unsigned wsum[4];
    int tid = threadIdx.x, blk = blockIdx.x;
    int b = blk / 1000, c = blk % 1000;
    float vlo = keyf(ws[ST_OFF + b * 4 + 0]);
    float vhi = keyf(ws[ST_OFF + b * 4 + 2]);
    double thr = (double)vlo + 0.1 * ((double)vhi - (double)vlo);
    unsigned run = ws[BC_OFF + b * 1000 + c];
    int lane = tid & 63, wid = tid >> 6;
    const float* cb = cube + (size_t)b * Nn;
    const float* db = dop + (size_t)b * Nn;
    for (int it = 0; it < 16; ++it) {
        int i = c * 4096 + it * 256 + tid;
        float x = cb[i];
        bool m = (double)x > thr;
        unsigned long long bal = __ballot(m);
        unsigned before = (unsigned)__popcll(bal & ((1ull << lane) - 1ull));
        if (lane == 0) wsum[wid] = (unsigned)__popcll(bal);
        __syncthreads();
        unsigned wbase = 0;
        for (int w = 0; w < wid; ++w) wbase += wsum[w];
        unsigned tot = wsum[0] + wsum[1] + wsum[2] + wsum[3];
        if (m) {
            unsigned k = run + wbase + before;
            size_t row = (size_t)b * Kn + k;
            int xi = i % 320;
            int t = i / 320;
            int yi = t % 320;
            int zi = t / 320;
            float xc = (float)xi / 320.0f * 72.0f;
            float yc = (float)yi / 320.0f * 32.0f;
            float zc = (float)zi / 40.0f * 8.0f;
            float pw = x / 1e13f;
            float dv = db[i] - 1.9326f;
            float* f = out + row * 5;
            f[0] = xc; f[1] = yc; f[2] = zc; f[3] = pw; f[4] = dv;
            float* s = out + OUT_SP + row * 4;
            s[0] = (float)b; s[1] = (float)zi; s[2] = (float)yi; s[3] = (float)xi;
            out[OUT_VAL + row] = 1.0f;
        }
        run += tot;
        __syncthreads();
    }
}

// ---------------- zero-fill invalid tail rows (output poisoned each launch) ----------------
__global__ void fill_k(float* __restrict__ out, const unsigned* __restrict__ ws) {
    int g = blockIdx.x * 256 + threadIdx.x;
    if (g >= Bn * Kn) return;
    int b = g / Kn;
    int k = g - b * Kn;
    if ((unsigned)k >= ws[CNT_OFF + b]) {
        size_t row = (size_t)g;
        float* f = out + row * 5;
        f[0] = 0.f; f[1] = 0.f; f[2] = 0.f; f[3] = 0.f; f[4] = 0.f;
        float* s = out + OUT_SP + row * 4;
        s[0] = 0.f; s[1] = 0.f; s[2] = 0.f; s[3] = 0.f;
        out[OUT_VAL + row] = 0.f;
    }
}

extern "C" void kernel_launch(void* const* d_in, const int* in_sizes, int n_in,
                              void* d_out, int out_size, void* d_ws, size_t ws_size,
                              hipStream_t stream) {
    const float* cube = (const float*)d_in[0];
    const float* dop = (const float*)d_in[1];
    float* out = (float*)d_out;
    unsigned* ws = (unsigned*)d_ws;

    // zero the histogram region only (state/bc/cnt are fully overwritten each call)
    hipMemsetAsync(d_ws, 0, 32768 * sizeof(unsigned), stream);

    hipLaunchKernelGGL(hist1_k, dim3(Bn * 250), dim3(256), 0, stream, cube, ws);
    hipLaunchKernelGGL(pick1_k, dim3(Bn), dim3(256), 0, stream, ws);
    hipLaunchKernelGGL(hist2_k, dim3(Bn * 250), dim3(256), 0, stream, cube, ws);
    hipLaunchKernelGGL(pick2_k, dim3(Bn * 2), dim3(256), 0, stream, ws);
    hipLaunchKernelGGL(hist3_k, dim3(Bn * 250), dim3(256), 0, stream, cube, ws);
    hipLaunchKernelGGL(pick3_k, dim3(Bn * 2), dim3(256), 0, stream, ws);
    hipLaunchKernelGGL(count_k, dim3(Bn * 1000), dim3(256), 0, stream, cube, ws);
    hipLaunchKernelGGL(scan_k, dim3(Bn), dim3(256), 0, stream, ws);
    hipLaunchKernelGGL(scatter_k, dim3(Bn * 1000), dim3(256), 0, stream, cube, dop, out, ws);
    hipLaunchKernelGGL(fill_k, dim3((Bn * Kn + 255) / 256), dim3(256), 0, stream, out, ws);
}